// Round 5
// baseline (818.085 us; speedup 1.0000x reference)
//
#include <hip/hip_runtime.h>

// RoIAlign (legacy/caffe-style, aligned=False variant per reference):
//   features: (B=4, C=1024, H=64, W=64) fp32
//   rois:     (N=2048, 5) fp32  [batch, x1, y1, x2, y2] in image coords
//   out:      (N, C, 7, 7) fp32
//
// v4 (2nd resubmit — rounds 3/4 died on container acquire, kernel never ran):
// v3's XCD channel-slice-major swizzle (each XCD sweeps one 2 MB
// channel-slice across all rois; feature bytes fetched from HBM once
// machine-wide) is kept verbatim. New here:
//  - LDS row-XOR quad swizzle: tile is [14 rows][8 quads], quad slot
//    sq^(row&7), row stride 32 floats, channel stride 456 (== 8 mod 32).
//    Kills the systematic ds_read conflicts (same-pw lanes across ph all hit
//    bank (4*rsu+col)%32 with the old stride-36 layout). Swizzle breaks
//    (ws,ws+1) adjacency, so each bin precomputes 4 scalar LDS offsets and
//    compute does 4 conflict-free ds_read_b32.
//  - T14 async-stage: issue chunk k+1's global float4 loads into regs
//    BEFORE computing chunk k; ds_write them after the post-compute barrier.
//    L2 latency hides under compute; LDS stays 17 KB -> 8 blocks/CU.

#define SCALE    0.0625f
#define C_       1024
#define H_       64
#define W_       64
#define HW       (H_ * W_)        // 4096
#define CHW      (C_ * HW)
#define AH_      7
#define AW_      7
#define NBIN     49               // 7*7
#define PER_ROI  (C_ * NBIN)      // 50176
#define QCH      32               // channels handled per block (slice)
#define NSLICE   (C_ / QCH)       // 32
#define CHUNK    8                // channels staged per iteration
#define RCAP     14               // max distinct rows: 7 ph values x {hs,hs+1}
#define QCAP     8                // max col-quads (data bound; fallback if exceeded)
#define TILE     456              // floats per channel tile: 14*32=448, +8 pad (456%32==8)
#define NXCD     8

__global__ __launch_bounds__(256, 8) void roialign_kernel(
    const float* __restrict__ feat,
    const float* __restrict__ rois,
    float* __restrict__ out,
    int N)
{
    __shared__ __align__(16) float s_data[CHUNK * TILE];  // 14592 B
    __shared__ float4 s_w[NBIN];     // corner weights (ul, ur, dl, dr)
    __shared__ int4   s_o[NBIN];     // swizzled LDS offsets (ul, ur, dl, dr)
    __shared__ int    s_goff[NBIN];  // hs*W + ws (fallback path)
    __shared__ int    s_rowG[RCAP];  // compacted slot -> global row
    __shared__ int    s_quadG[16];   // compacted slot -> global col-quad
    __shared__ int    s_R, s_Q, s_b;

    // ---- XCD-aware decode: blockIdx = ((slice_sub*N + roi) << 3) | xcd ----
    // Consecutive blocks round-robin across XCDs (idx % 8); with slice_sub
    // slowest, each XCD sees one 2 MB channel-slice at a time, swept across
    // all rois -> slice stays resident in its private L2.
    const unsigned bidx = blockIdx.x;
    const int xcd       = (int)(bidx & (NXCD - 1));
    const unsigned tmp  = bidx >> 3;
    const int roi       = (int)(tmp % (unsigned)N);
    const int slice_sub = (int)(tmp / (unsigned)N);      // [0, NSLICE/NXCD)
    const int slice     = slice_sub * NXCD + xcd;        // [0, NSLICE)
    const int t = threadIdx.x;

    unsigned long long rm = 0ull;   // row occupancy mask (wave 0)
    unsigned int       qm = 0u;     // col-quad occupancy mask (wave 0)

    if (t < 64) {
        int hs = 0, ws = 0;
        if (t < NBIN) {
            // Match numpy rounding exactly: no FMA contraction here, so floor()
            // boundary decisions agree with the reference bit-for-bit.
            #pragma clang fp contract(off)
            const float r0 = rois[roi * 5 + 0];
            const float r1 = rois[roi * 5 + 1];
            const float r2 = rois[roi * 5 + 2];
            const float r3 = rois[roi * 5 + 3];
            const float r4 = rois[roi * 5 + 4];
            const int   b  = (int)r0;
            const float x1 = r1 * SCALE;
            const float y1 = r2 * SCALE;
            const float x2 = r3 * SCALE;
            const float y2 = r4 * SCALE;
            const float roi_w = fmaxf(x2 - x1, 0.0f);
            const float roi_h = fmaxf(y2 - y1, 0.0f);
            const float bin_w = roi_w / (float)(AW_ - 1);  // IEEE divide
            const float bin_h = roi_h / (float)(AH_ - 1);

            const int ph = t / AW_;
            const int pw = t - ph * AW_;

            const float h = y1 + (float)ph * bin_h;
            const float w = x1 + (float)pw * bin_w;

            const float hstart = fminf(floorf(h), (float)(H_ - 2));
            const float wstart = fminf(floorf(w), (float)(W_ - 2));
            const float hr = h - hstart;
            const float wr = w - wstart;

            const bool valid = (h >= 0.0f) && (h < (float)H_) &&
                               (w >= 0.0f) && (w < (float)W_);

            hs = min(max((int)hstart, 0), H_ - 2);
            ws = min(max((int)wstart, 0), W_ - 2);

            float wul = (1.0f - hr) * (1.0f - wr);
            float wur = (1.0f - hr) * wr;
            float wdl = hr * (1.0f - wr);
            float wdr = hr * wr;
            if (!valid) { wul = 0.0f; wur = 0.0f; wdl = 0.0f; wdr = 0.0f; }

            s_w[t]    = make_float4(wul, wur, wdl, wdr);
            s_goff[t] = hs * W_ + ws;
            if (t == 0) s_b = b;

            rm = 3ull << hs;                                   // rows hs, hs+1
            qm = (1u << (ws >> 2)) | (1u << ((ws + 1) >> 2));  // quads of ws, ws+1
        }

        // Wave-0 OR-reduction: all 64 lanes end with the full masks.
        #pragma unroll
        for (int d = 1; d < 64; d <<= 1) {
            rm |= __shfl_xor(rm, d);
            qm |= __shfl_xor(qm, d);
        }

        // Compacted slot -> global tables, built in parallel.
        if ((rm >> t) & 1ull)
            s_rowG[__popcll(rm & ((1ull << t) - 1ull))] = t;
        if (t < 16 && ((qm >> t) & 1u))
            s_quadG[__popc(qm & ((1u << t) - 1u))] = t;
        if (t == 0) { s_R = (int)__popcll(rm); s_Q = __popc(qm); }

        // Per-bin swizzled LDS offsets (masks live in regs).
        if (t < NBIN) {
            const int rsu = __popcll(rm & ((1ull << hs) - 1ull));   // slot(hs)
            const int rsd = __popcll(rm & ((2ull << hs) - 1ull));   // slot(hs+1)
            const int w1  = ws + 1;
            const int sq0 = __popc(qm & ((1u << (ws >> 2)) - 1u));  // quad slot of ws
            const int sq1 = __popc(qm & ((1u << (w1 >> 2)) - 1u));  // quad slot of ws+1
            const int e0  = ws & 3;
            const int e1  = w1 & 3;
            s_o[t] = make_int4(
                rsu * 32 + ((sq0 ^ (rsu & 7)) << 2) + e0,   // ul
                rsu * 32 + ((sq1 ^ (rsu & 7)) << 2) + e1,   // ur
                rsd * 32 + ((sq0 ^ (rsd & 7)) << 2) + e0,   // dl
                rsd * 32 + ((sq1 ^ (rsd & 7)) << 2) + e1);  // dr
        }
    }
    __syncthreads();

    const int R  = s_R;
    const int Qn = s_Q;
    const int rq = R * Qn;

    const float* featC = feat + (size_t)s_b * CHW + (size_t)(slice * QCH) * HW;
    float*       ob    = out + (size_t)roi * PER_ROI + (size_t)(slice * QCH) * NBIN;

    if (Qn > QCAP || R > RCAP) {
        // General-case fallback: direct gather.
        for (int e = t; e < QCH * NBIN; e += 256) {
            const unsigned eu  = (unsigned)e;
            const unsigned c   = eu / NBIN;        // magic-mul division
            const unsigned bin = eu - c * NBIN;
            const float4 wg  = s_w[bin];
            const int    off = s_goff[bin] + (int)(c << 12);
            const float ul = featC[off];
            const float ur = featC[off + 1];
            const float dl = featC[off + W_];
            const float dr = featC[off + W_ + 1];
            const float v = ul * wg.x + ur * wg.y + dl * wg.z + dr * wg.w;
            __builtin_nontemporal_store(v, ob + e);
        }
        return;
    }

    // ---- per-thread load slots (constant across chunks): j = t + 256*i ----
    // rq*CHUNK <= 112*8 = 896 -> at most 4 slots/thread.
    const int rqC = rq * CHUNK;
    int  gOffA[4], lOffA[4];
    bool actA[4];
    #pragma unroll
    for (int i = 0; i < 4; ++i) {
        const int j = t + 256 * i;
        actA[i] = (j < rqC);
        int g = 0, l = 0;
        if (actA[i]) {
            const int ch  = j / rq;            // runtime div, once per block
            const int idx = j - ch * rq;
            const int r_  = idx / Qn;
            const int sq  = idx - r_ * Qn;
            const int qq  = sq ^ (r_ & 7);     // row-XOR quad swizzle (write side)
            g = ch * HW + s_rowG[r_] * W_ + s_quadG[sq] * 4;
            l = ch * TILE + r_ * 32 + qq * 4;
        }
        gOffA[i] = g; lOffA[i] = l;
    }

    // ---- per-thread compute mapping: fixed bin, params in registers ----
    const int cl0 = t / NBIN;                 // compile-time magic div
    const int bin = t - cl0 * NBIN;
    const bool computeActive = (t < 5 * NBIN);  // 245 threads
    float4 w4 = make_float4(0.f, 0.f, 0.f, 0.f);
    int4   oo = make_int4(0, 0, 0, 0);
    if (computeActive) { w4 = s_w[bin]; oo = s_o[bin]; }

    // ---- prologue: stage chunk 0 ----
    float4 pf[4];
    #pragma unroll
    for (int i = 0; i < 4; ++i)
        if (actA[i]) pf[i] = *(const float4*)(featC + gOffA[i]);
    #pragma unroll
    for (int i = 0; i < 4; ++i)
        if (actA[i]) *(float4*)(&s_data[lOffA[i]]) = pf[i];
    __syncthreads();

    for (int cc = 0; cc < QCH; cc += CHUNK) {
        const bool more = (cc + CHUNK) < QCH;

        // T14 issue-early: next chunk's global loads go in flight now; their
        // ~200-400 cyc L2 latency hides under this chunk's compute.
        if (more) {
            const float* src = featC + (size_t)(cc + CHUNK) * HW;
            #pragma unroll
            for (int i = 0; i < 4; ++i)
                if (actA[i]) pf[i] = *(const float4*)(src + gOffA[i]);
        }

        if (computeActive) {
            #pragma unroll
            for (int k = 0; k < 2; ++k) {
                const int cl = cl0 + 5 * k;
                if (cl < CHUNK) {
                    const float* tb = s_data + cl * TILE;
                    const float vul = tb[oo.x];
                    const float vur = tb[oo.y];
                    const float vdl = tb[oo.z];
                    const float vdr = tb[oo.w];
                    const float v = vul * w4.x + vur * w4.y + vdl * w4.z + vdr * w4.w;
                    __builtin_nontemporal_store(v, ob + (cc + cl) * NBIN + bin);
                }
            }
        }
        __syncthreads();   // all reads of this chunk done

        // T14 write-late: park the prefetched regs into LDS.
        if (more) {
            #pragma unroll
            for (int i = 0; i < 4; ++i)
                if (actA[i]) *(float4*)(&s_data[lOffA[i]]) = pf[i];
        }
        __syncthreads();   // writes visible for next iteration
    }
}

extern "C" void kernel_launch(void* const* d_in, const int* in_sizes, int n_in,
                              void* d_out, int out_size, void* d_ws, size_t ws_size,
                              hipStream_t stream) {
    const float* feat = (const float*)d_in[0];
    const float* rois = (const float*)d_in[1];
    float* out = (float*)d_out;
    const int N = in_sizes[1] / 5;  // 2048
    dim3 grid((unsigned)N * NSLICE);
    dim3 block(256);
    roialign_kernel<<<grid, block, 0, stream>>>(feat, rois, out, N);
}